// Round 6
// baseline (194.648 us; speedup 1.0000x reference)
//
#include <hip/hip_runtime.h>
#include <hip/hip_bf16.h>
#include <cstdint>

#define NCLS 80
#define GNUM 16
#define BNUM 16
#define A0   25600
#define A1   6400
#define A2   1600
#define ATOT 33600
#define QTOT 16800                      // ATOT/2 anchor-pairs
#define NBLK_A 132
#define NBLK_TOTAL (NBLK_A*BNUM)        // 2112 blocks in loss grid
#define NSPLIT 8
#define SEG   4200
#define WSEG  1050
#define NWAVE 32
#define FINF  3.4e38f
#define IINF  0x7fffffff

__device__ __forceinline__ float rcpf(float x){ return __builtin_amdgcn_rcpf(x); }
__device__ __forceinline__ float sqf (float x){ return __builtin_amdgcn_sqrtf(x); }
__device__ __forceinline__ float rsqf(float x){ return __builtin_amdgcn_rsqf(x); }

__device__ __forceinline__ float bce(float x, float t){
  float e = __expf(-fabsf(x));
  return fmaxf(x,0.f) - x*t + __logf(1.f + e);
}

__device__ __forceinline__ void get_level(const float* p0, const float* p1, const float* p2,
                                          int a, const float*& p, int& hw, int& off, int& W, float& s)
{
  if (a < A0){ p=p0; hw=A0; off=a; W=160; s=8.f; }
  else if (a < A0+A1){ p=p1; hw=A1; off=a-A0; W=80; s=16.f; }
  else { p=p2; hw=A2; off=a-A0-A1; W=40; s=32.f; }
}

// ---------------- Kernel A: decode + per-(g,a) cost, 2 anchors/thread ----------------
// MLP-first structure: 2 batches of 40 fully-unrolled float2 loads (static reg indexing),
// group-of-8 products identical to prior passing version (bit-identical base).
__global__ __launch_bounds__(256, 4) void decode_cost_kernel(
    const float* __restrict__ p0, const float* __restrict__ p1, const float* __restrict__ p2,
    const float* __restrict__ labels,
    float* __restrict__ cost, float4* __restrict__ pbox, float* __restrict__ pconf,
    unsigned char* __restrict__ unionm)
{
  const int b = blockIdx.y;
  const int q = blockIdx.x*256 + threadIdx.x;
  __shared__ float s_tb[GNUM][4];
  __shared__ int   s_tc[GNUM];
  if (threadIdx.x < GNUM){
    const float* L = labels + ((size_t)b*GNUM + threadIdx.x)*5;
    s_tb[threadIdx.x][0]=L[0]; s_tb[threadIdx.x][1]=L[1];
    s_tb[threadIdx.x][2]=L[2]; s_tb[threadIdx.x][3]=L[3];
    s_tc[threadIdx.x]=(int)L[4];
  }
  __syncthreads();
  if (q >= QTOT) return;
  const int a0 = q*2;

  const float* p; int hw, off, W; float s;
  get_level(p0,p1,p2,a0,p,hw,off,W,s);
  const float* bp = p + (size_t)b*(NCLS+5)*hw + off;

  const float2 RX = *(const float2*)(bp);
  const float2 RY = *(const float2*)(bp + (size_t)hw);
  const float2 RW = *(const float2*)(bp + 2*(size_t)hw);
  const float2 RH = *(const float2*)(bp + 3*(size_t)hw);
  const float2 CL = *(const float2*)(bp + 4*(size_t)hw);

  int gx0 = off % W, gy0 = off / W;
  int gx1 = gx0+1, gy1 = gy0; if (gx1 >= W){ gx1 = 0; gy1++; }

  const float sc0 = rcpf(1.f + __expf(-CL.x));
  const float sc1 = rcpf(1.f + __expf(-CL.y));
  const float ssc0 = sqf(sc0),   ssc1 = sqf(sc1);     // sqrt(sc)
  const float rssc0 = rcpf(ssc0), rssc1 = rcpf(ssc1); // 1/sqrt(sc)

  const float* cp = bp + 5*(size_t)hw;
  float base0=0.f, base1=0.f;

  // ---- batch 1: classes 0..39, loads fully unrolled then grouped products ----
  {
    float2 xv[40];
    #pragma unroll
    for (int j=0;j<40;j++) xv[j] = *(const float2*)(cp + (size_t)j*hw);
    #pragma unroll
    for (int grp=0; grp<5; grp++){
      float pr0=1.f, pr1=1.f;
      #pragma unroll
      for (int jj=0;jj<8;jj++){
        const float2 x = xv[grp*8+jj];
        pr0 *= (1.f - ssc0*rsqf(1.f+__expf(-x.x)));
        pr1 *= (1.f - ssc1*rsqf(1.f+__expf(-x.y)));
      }
      base0 -= __logf(pr0);
      base1 -= __logf(pr1);
    }
  }
  // ---- batch 2: classes 40..79 ----
  {
    float2 xv[40];
    #pragma unroll
    for (int j=0;j<40;j++) xv[j] = *(const float2*)(cp + (size_t)(40+j)*hw);
    #pragma unroll
    for (int grp=0; grp<5; grp++){
      float pr0=1.f, pr1=1.f;
      #pragma unroll
      for (int jj=0;jj<8;jj++){
        const float2 x = xv[grp*8+jj];
        pr0 *= (1.f - ssc0*rsqf(1.f+__expf(-x.x)));
        pr1 *= (1.f - ssc1*rsqf(1.f+__expf(-x.y)));
      }
      base0 -= __logf(pr0);
      base1 -= __logf(pr1);
    }
  }

  // decode boxes
  const float px0=(RX.x+gx0)*s, py0=(RY.x+gy0)*s, pw0=__expf(RW.x)*s, ph0=__expf(RH.x)*s;
  const float px1=(RX.y+gx1)*s, py1=(RY.y+gy1)*s, pw1=__expf(RW.y)*s, ph1=__expf(RH.y)*s;
  const float xc0=(gx0+0.5f)*s, yc0=(gy0+0.5f)*s;
  const float xc1=(gx1+0.5f)*s, yc1=(gy1+0.5f)*s;
  const float q1x0=px0-pw0*0.5f, q2x0=px0+pw0*0.5f, q1y0=py0-ph0*0.5f, q2y0=py0+ph0*0.5f;
  const float q1x1=px1-pw1*0.5f, q2x1=px1+pw1*0.5f, q1y1=py1-ph1*0.5f, q2y1=py1+ph1*0.5f;
  const float areaP0 = pw0*ph0, areaP1 = pw1*ph1;
  const float r = 2.5f*s;

  // union flags (register-only pre-pass)
  bool un0=false, un1=false;
  #pragma unroll
  for (int g=0;g<GNUM;g++){
    const float bx=s_tb[g][0], by=s_tb[g][1], bw=s_tb[g][2], bh=s_tb[g][3];
    const float b1x=bx-bw*0.5f, b2x=bx+bw*0.5f, b1y=by-bh*0.5f, b2y=by+bh*0.5f;
    un0 = un0 || ((xc0>b1x)&&(xc0<b2x)&&(yc0>b1y)&&(yc0<b2y))
              || ((xc0>bx-r)&&(xc0<bx+r)&&(yc0>by-r)&&(yc0<by+r));
    un1 = un1 || ((xc1>b1x)&&(xc1<b2x)&&(yc1>b1y)&&(yc1<b2y))
              || ((xc1>bx-r)&&(xc1<bx+r)&&(yc1>by-r)&&(yc1<by+r));
  }
  const float add0 = un0?0.f:1e9f, add1 = un1?0.f:1e9f;

  // per-g: target-class delta + iou + cost; unroll 4 clusters the gather loads
  const size_t rowb = (size_t)b*GNUM*ATOT + a0;
  #pragma unroll 4
  for (int g=0;g<GNUM;g++){
    const float2 x = *(const float2*)(cp + (size_t)s_tc[g]*hw);
    const float e0 = __expf(-x.x), e1 = __expf(-x.y);
    const float rp0 = rssc0*sqf(1.f+e0), rp1 = rssc1*sqf(1.f+e1); // 1/p
    const float cd0 = __logf(fmaxf(rp0-1.f, 1e-30f));
    const float cd1 = __logf(fmaxf(rp1-1.f, 1e-30f));

    const float bx=s_tb[g][0], by=s_tb[g][1], bw=s_tb[g][2], bh=s_tb[g][3];
    const float b1x=bx-bw*0.5f, b2x=bx+bw*0.5f, b1y=by-bh*0.5f, b2y=by+bh*0.5f;
    const float areaB = bw*bh;

    const bool inb0 = (xc0>b1x)&&(xc0<b2x)&&(yc0>b1y)&&(yc0<b2y);
    const bool inm0 = (xc0>bx-r)&&(xc0<bx+r)&&(yc0>by-r)&&(yc0<by+r);
    const bool inb1 = (xc1>b1x)&&(xc1<b2x)&&(yc1>b1y)&&(yc1<b2y);
    const bool inm1 = (xc1>bx-r)&&(xc1<bx+r)&&(yc1>by-r)&&(yc1<by+r);

    float iw,ih,inte;
    iw = fmaxf(fminf(b2x,q2x0)-fmaxf(b1x,q1x0),0.f);
    ih = fmaxf(fminf(b2y,q2y0)-fmaxf(b1y,q1y0),0.f);
    inte = iw*ih;
    const float iou0 = inte * rcpf(areaB+areaP0-inte+1e-16f);
    iw = fmaxf(fminf(b2x,q2x1)-fmaxf(b1x,q1x1),0.f);
    ih = fmaxf(fminf(b2y,q2y1)-fmaxf(b1y,q1y1),0.f);
    inte = iw*ih;
    const float iou1 = inte * rcpf(areaB+areaP1-inte+1e-16f);

    float2 cst;
    cst.x = base0 + cd0 - 3.f*__logf(iou0+1e-8f) + ((inb0&&inm0)?0.f:100000.f) + add0;
    cst.y = base1 + cd1 - 3.f*__logf(iou1+1e-8f) + ((inb1&&inm1)?0.f:100000.f) + add1;
    *(float2*)(cost + rowb + (size_t)g*ATOT) = cst;
  }

  pbox[(size_t)b*ATOT+a0  ] = make_float4(px0,py0,pw0,ph0);
  pbox[(size_t)b*ATOT+a0+1] = make_float4(px1,py1,pw1,ph1);
  *(float2*)(pconf + (size_t)b*ATOT + a0) = make_float2(CL.x, CL.y);
  uchar2 um; um.x = un0?1:0; um.y = un1?1:0;
  *(uchar2*)(unionm + (size_t)b*ATOT + a0) = um;
}

// ---------------- Kernel B1: per-(b,g,wave) top-10 via wave shuffles ----------------
__global__ __launch_bounds__(256) void topk_stage1(
    const float* __restrict__ cost, const float4* __restrict__ pbox,
    const unsigned char* __restrict__ unionm, const float* __restrict__ labels,
    float* __restrict__ cand_c, int* __restrict__ cand_i, float* __restrict__ cand_v)
{
  const int bg   = blockIdx.y;
  const int b    = bg >> 4;
  const int seg  = blockIdx.x;
  const int wave = threadIdx.x >> 6;
  const int lane = threadIdx.x & 63;
  const int wg   = seg*4 + wave;

  const float*  crow = cost + (size_t)bg*ATOT;
  const float4* prow = pbox + (size_t)b*ATOT;
  const unsigned char* urow = unionm + (size_t)b*ATOT;
  const float bx = labels[bg*5+0], by = labels[bg*5+1];
  const float bw = labels[bg*5+2], bh = labels[bg*5+3];
  const float areaB = bw*bh;
  const float b1x=bx-bw*0.5f, b2x=bx+bw*0.5f, b1y=by-bh*0.5f, b2y=by+bh*0.5f;

  const int start = seg*SEG + wave*WSEG;
  const int end   = start + WSEG;

  float cv[10]; int ci[10]; float iv[10];
  #pragma unroll
  for (int k=0;k<10;k++){ cv[k]=FINF; ci[k]=IINF; iv[k]=0.f; }

  for (int a = start + lane; a < end; a += 64){
    float c = crow[a];
    if (c < cv[9] || (c == cv[9] && a < ci[9])){
      float nc=c; int ni=a;
      #pragma unroll
      for (int k=0;k<10;k++){
        bool better = (nc < cv[k]) || (nc==cv[k] && ni<ci[k]);
        float tv=cv[k]; int ti=ci[k];
        cv[k]=better?nc:cv[k]; ci[k]=better?ni:ci[k];
        nc  =better?tv:nc;     ni  =better?ti:ni;
      }
    }
    if (urow[a]){
      float4 pb = prow[a];
      float tlx=fmaxf(b1x, pb.x-pb.z*0.5f), brx=fminf(b2x, pb.x+pb.z*0.5f);
      float tly=fmaxf(b1y, pb.y-pb.w*0.5f), bry=fminf(b2y, pb.y+pb.w*0.5f);
      float iw=fmaxf(brx-tlx,0.f), ih=fmaxf(bry-tly,0.f);
      float inte=iw*ih;
      float io = inte * rcpf(areaB + pb.z*pb.w - inte + 1e-16f);
      if (io > iv[9]){
        float nv=io;
        #pragma unroll
        for (int k=0;k<10;k++){
          bool better = nv > iv[k];
          float tv=iv[k];
          iv[k]=better?nv:iv[k];
          nv  =better?tv:nv;
        }
      }
    }
  }

  float selc = 0.f; int seli = 0;
  #pragma unroll
  for (int r=0;r<10;r++){
    float bv = cv[0]; int bi = ci[0];
    #pragma unroll
    for (int off=32; off>0; off>>=1){
      float ov = __shfl_xor(bv, off);
      int   oi = __shfl_xor(bi, off);
      bool take = (ov < bv) || (ov==bv && oi<bi);
      bv = take?ov:bv; bi = take?oi:bi;
    }
    if (lane == r){ selc = bv; seli = bi; }
    if (cv[0]==bv && ci[0]==bi){
      #pragma unroll
      for (int k=0;k<9;k++){ cv[k]=cv[k+1]; ci[k]=ci[k+1]; }
      cv[9]=FINF; ci[9]=IINF;
    }
  }
  float selv = 0.f;
  #pragma unroll
  for (int r=0;r<10;r++){
    float bv = iv[0]; int bl = lane;
    #pragma unroll
    for (int off=32; off>0; off>>=1){
      float ov = __shfl_xor(bv, off);
      int   ol = __shfl_xor(bl, off);
      bool take = (ov > bv) || (ov==bv && ol<bl);
      bv = take?ov:bv; bl = take?ol:bl;
    }
    if (lane == r) selv = bv;
    if (lane == bl){
      #pragma unroll
      for (int k=0;k<9;k++){ iv[k]=iv[k+1]; }
      iv[9]=0.f;
    }
  }

  if (lane < 10){
    const size_t base = ((size_t)bg*NWAVE + wg)*10 + lane;
    cand_c[base] = selc;
    cand_i[base] = seli;
    cand_v[base] = selv;
  }
}

// ---------------- Kernel B2: merge 32x10 candidates -> top-10 + dyn_k + scatter ----------------
__global__ __launch_bounds__(64) void topk_stage2(
    const float* __restrict__ cand_c, const int* __restrict__ cand_i,
    const float* __restrict__ cand_v, unsigned int* __restrict__ match_mask)
{
  const int bg = blockIdx.x;
  const int b = bg >> 4, g = bg & 15;
  const int lane = threadIdx.x;
  const size_t base = (size_t)bg*NWAVE*10 + lane*5;

  float cv[5]; int ci[5]; float iv[5];
  #pragma unroll
  for (int k=0;k<5;k++){ cv[k]=cand_c[base+k]; ci[k]=cand_i[base+k]; iv[k]=cand_v[base+k]; }

  int seli = 0;
  #pragma unroll
  for (int r=0;r<10;r++){
    float bv = cv[0]; int bi = ci[0];
    #pragma unroll
    for (int off=32; off>0; off>>=1){
      float ov = __shfl_xor(bv, off);
      int   oi = __shfl_xor(bi, off);
      bool take = (ov < bv) || (ov==bv && oi<bi);
      bv = take?ov:bv; bi = take?oi:bi;
    }
    if (lane == r) seli = bi;
    if (cv[0]==bv && ci[0]==bi){
      #pragma unroll
      for (int k=0;k<4;k++){ cv[k]=cv[k+1]; ci[k]=ci[k+1]; }
      cv[4]=FINF; ci[4]=IINF;
    }
  }

  float isum = 0.f;
  #pragma unroll
  for (int r=0;r<10;r++){
    float bv = iv[0]; int bl = lane;
    #pragma unroll
    for (int off=32; off>0; off>>=1){
      float ov = __shfl_xor(bv, off);
      int   ol = __shfl_xor(bl, off);
      bool take = (ov > bv) || (ov==bv && ol<bl);
      bv = take?ov:bv; bl = take?ol:bl;
    }
    isum += bv;
    if (lane == bl){
      #pragma unroll
      for (int k=0;k<4;k++){ iv[k]=iv[k+1]; }
      iv[4]=0.f;
    }
  }

  int dynk = (int)isum;
  if (dynk < 1)  dynk = 1;
  if (dynk > 10) dynk = 10;
  if (lane < dynk)
    atomicOr(&match_mask[(size_t)b*ATOT + seli], 1u<<g);
}

// ---------------- Kernel C: resolve matches + loss accumulation ----------------
__global__ __launch_bounds__(256) void loss_kernel(
    const float* __restrict__ p0, const float* __restrict__ p1, const float* __restrict__ p2,
    const float* __restrict__ labels,
    const float* __restrict__ cost, const float4* __restrict__ pbox,
    const float* __restrict__ pconf, const unsigned int* __restrict__ match_mask,
    float* __restrict__ blocksums)
{
  const int b = blockIdx.y;
  const int a = blockIdx.x*256 + threadIdx.x;
  float lbox=0.f, lconf=0.f, lcls=0.f, fgn=0.f;
  if (a < ATOT){
    unsigned int m = match_mask[(size_t)b*ATOT+a];
    float cl = pconf[(size_t)b*ATOT+a];
    if (m != 0u){
      int gidx;
      if (__popc(m) > 1){
        float best = FINF; int bgi = 0;
        for (int g=0; g<GNUM; g++){
          float c = cost[((size_t)b*GNUM+g)*ATOT + a];
          if (c < best){ best=c; bgi=g; }
        }
        gidx = bgi;
      } else {
        gidx = __ffs(m)-1;
      }
      const float* L = labels + ((size_t)b*GNUM+gidx)*5;
      float bx=L[0], by=L[1], bw=L[2], bh=L[3];
      int tcg=(int)L[4];
      float4 pb = pbox[(size_t)b*ATOT+a];
      float tlx=fmaxf(bx-bw*0.5f, pb.x-pb.z*0.5f);
      float brx=fminf(bx+bw*0.5f, pb.x+pb.z*0.5f);
      float tly=fmaxf(by-bh*0.5f, pb.y-pb.w*0.5f);
      float bry=fminf(by+bh*0.5f, pb.y+pb.w*0.5f);
      float iw=fmaxf(brx-tlx,0.f), ih=fmaxf(bry-tly,0.f);
      float inte=iw*ih;
      float iou = inte * rcpf(bw*bh + pb.z*pb.w - inte + 1e-16f);
      lbox = 1.f - iou*iou;
      lconf = bce(cl, 1.f);
      float miou = iou;
      const float* p; int hw, off, W; float s;
      get_level(p0,p1,p2,a,p,hw,off,W,s);
      const float* bp = p + (size_t)b*(NCLS+5)*hw + off;
      for (int c=0;c<NCLS;c++){
        float x = bp[(size_t)(5+c)*hw];
        float t = (c==tcg)? miou : 0.f;
        lcls += bce(x, t);
      }
      fgn = 1.f;
    } else {
      lconf = bce(cl, 0.f);
    }
  }
  #pragma unroll
  for (int off2=32; off2>0; off2>>=1){
    lbox  += __shfl_down(lbox,  off2);
    lconf += __shfl_down(lconf, off2);
    lcls  += __shfl_down(lcls,  off2);
    fgn   += __shfl_down(fgn,   off2);
  }
  __shared__ float s_red[4][4];
  const int wave = threadIdx.x >> 6;
  if ((threadIdx.x & 63)==0){
    s_red[wave][0]=lbox; s_red[wave][1]=lconf; s_red[wave][2]=lcls; s_red[wave][3]=fgn;
  }
  __syncthreads();
  if (threadIdx.x==0){
    float r0=0,r1=0,r2=0,r3=0;
    #pragma unroll
    for (int w=0;w<4;w++){ r0+=s_red[w][0]; r1+=s_red[w][1]; r2+=s_red[w][2]; r3+=s_red[w][3]; }
    const int bid = blockIdx.y*gridDim.x + blockIdx.x;
    ((float4*)blocksums)[bid] = make_float4(r0,r1,r2,r3);
  }
}

__global__ __launch_bounds__(256) void finalize_kernel(
    const float* __restrict__ blocksums, float* __restrict__ out)
{
  const int tid = threadIdx.x;
  float r0=0,r1=0,r2=0,r3=0;
  for (int i = tid; i < NBLK_TOTAL; i += 256){
    const float4 v = ((const float4*)blocksums)[i];
    r0+=v.x; r1+=v.y; r2+=v.z; r3+=v.w;
  }
  #pragma unroll
  for (int off=32; off>0; off>>=1){
    r0 += __shfl_down(r0, off);
    r1 += __shfl_down(r1, off);
    r2 += __shfl_down(r2, off);
    r3 += __shfl_down(r3, off);
  }
  __shared__ float s_red[4][4];
  const int wave = tid >> 6;
  if ((tid & 63)==0){ s_red[wave][0]=r0; s_red[wave][1]=r1; s_red[wave][2]=r2; s_red[wave][3]=r3; }
  __syncthreads();
  if (tid==0){
    float t0=0,t1=0,t2=0,t3=0;
    #pragma unroll
    for (int w=0;w<4;w++){ t0+=s_red[w][0]; t1+=s_red[w][1]; t2+=s_red[w][2]; t3+=s_red[w][3]; }
    out[0] = (5.f*t0 + t1 + t2) / fmaxf(t3, 1.f);
  }
}

extern "C" void kernel_launch(void* const* d_in, const int* in_sizes, int n_in,
                              void* d_out, int out_size, void* d_ws, size_t ws_size,
                              hipStream_t stream)
{
  const float* p0     = (const float*)d_in[0];
  const float* p1     = (const float*)d_in[1];
  const float* p2     = (const float*)d_in[2];
  const float* labels = (const float*)d_in[3];

  char* ws = (char*)d_ws;
  size_t o = 0;
  float*        cost       = (float*)(ws + o);        o += (size_t)BNUM*GNUM*ATOT*4;
  float4*       pbox       = (float4*)(ws + o);       o += (size_t)BNUM*ATOT*16;
  float*        pconf      = (float*)(ws + o);        o += (size_t)BNUM*ATOT*4;
  unsigned int* match_mask = (unsigned int*)(ws + o); o += (size_t)BNUM*ATOT*4;
  unsigned char* unionm    = (unsigned char*)(ws + o);o += (size_t)BNUM*ATOT;
  o = (o + 255) & ~(size_t)255;
  float*        blocksums  = (float*)(ws + o);        o += (size_t)NBLK_TOTAL*4*4;
  o = (o + 255) & ~(size_t)255;
  float*        cand_c     = (float*)(ws + o);        o += (size_t)256*NWAVE*10*4;
  int*          cand_i     = (int*)(ws + o);          o += (size_t)256*NWAVE*10*4;
  float*        cand_v     = (float*)(ws + o);        o += (size_t)256*NWAVE*10*4;

  hipMemsetAsync(match_mask, 0, (size_t)BNUM*ATOT*4, stream);

  dim3 gridA((QTOT+255)/256, BNUM);                 // 66 x 16, 2 anchors/thread
  decode_cost_kernel<<<gridA, 256, 0, stream>>>(p0,p1,p2,labels,cost,pbox,pconf,unionm);
  dim3 gridT(NSPLIT, BNUM*GNUM);
  topk_stage1<<<gridT, 256, 0, stream>>>(cost, pbox, unionm, labels, cand_c, cand_i, cand_v);
  topk_stage2<<<BNUM*GNUM, 64, 0, stream>>>(cand_c, cand_i, cand_v, match_mask);
  dim3 gridC(NBLK_A, BNUM);
  loss_kernel<<<gridC, 256, 0, stream>>>(p0,p1,p2,labels,cost,pbox,pconf,match_mask,blocksums);
  finalize_kernel<<<1, 256, 0, stream>>>(blocksums, (float*)d_out);
}

// Round 7
// 147.700 us; speedup vs baseline: 1.3179x; 1.3179x over previous
//
#include <hip/hip_runtime.h>
#include <hip/hip_bf16.h>
#include <cstdint>

#define NCLS 80
#define GNUM 16
#define BNUM 16
#define A0   25600
#define A1   6400
#define A2   1600
#define ATOT 33600
#define QTOT 16800                      // ATOT/2 anchor-pairs
#define NBLK_A 132
#define NBLK_TOTAL (NBLK_A*BNUM)        // 2112 blocks in loss grid
#define NSPLIT 8
#define SEG   4200
#define WSEG  1050
#define NWAVE 32
#define FINF  3.4e38f
#define IINF  0x7fffffff

__device__ __forceinline__ float rcpf(float x){ return __builtin_amdgcn_rcpf(x); }
__device__ __forceinline__ float sqf (float x){ return __builtin_amdgcn_sqrtf(x); }
__device__ __forceinline__ float rsqf(float x){ return __builtin_amdgcn_rsqf(x); }

__device__ __forceinline__ float bce(float x, float t){
  float e = __expf(-fabsf(x));
  return fmaxf(x,0.f) - x*t + __logf(1.f + e);
}

__device__ __forceinline__ void get_level(const float* p0, const float* p1, const float* p2,
                                          int a, const float*& p, int& hw, int& off, int& W, float& s)
{
  if (a < A0){ p=p0; hw=A0; off=a; W=160; s=8.f; }
  else if (a < A0+A1){ p=p1; hw=A1; off=a-A0; W=80; s=16.f; }
  else { p=p2; hw=A2; off=a-A0-A1; W=40; s=32.f; }
}

// ---------------- Kernel A: decode + per-(g,a) cost, 2 anchors/thread ----------------
// Batches of 16 float2 loads (32 classes -> 2 product-groups of 8, same order as the
// passing round-5 version) + prefetched target-class gathers. Array budget 64 VGPR.
__global__ __launch_bounds__(256, 4) void decode_cost_kernel(
    const float* __restrict__ p0, const float* __restrict__ p1, const float* __restrict__ p2,
    const float* __restrict__ labels,
    float* __restrict__ cost, float4* __restrict__ pbox, float* __restrict__ pconf,
    unsigned char* __restrict__ unionm)
{
  const int b = blockIdx.y;
  const int q = blockIdx.x*256 + threadIdx.x;
  __shared__ float s_tb[GNUM][4];
  __shared__ int   s_tc[GNUM];
  if (threadIdx.x < GNUM){
    const float* L = labels + ((size_t)b*GNUM + threadIdx.x)*5;
    s_tb[threadIdx.x][0]=L[0]; s_tb[threadIdx.x][1]=L[1];
    s_tb[threadIdx.x][2]=L[2]; s_tb[threadIdx.x][3]=L[3];
    s_tc[threadIdx.x]=(int)L[4];
  }
  __syncthreads();
  if (q >= QTOT) return;
  const int a0 = q*2;

  const float* p; int hw, off, W; float s;
  get_level(p0,p1,p2,a0,p,hw,off,W,s);
  const float* bp = p + (size_t)b*(NCLS+5)*hw + off;

  const float2 RX = *(const float2*)(bp);
  const float2 RY = *(const float2*)(bp + (size_t)hw);
  const float2 RW = *(const float2*)(bp + 2*(size_t)hw);
  const float2 RH = *(const float2*)(bp + 3*(size_t)hw);
  const float2 CL = *(const float2*)(bp + 4*(size_t)hw);
  const float* cp = bp + 5*(size_t)hw;

  // prefetch the 16 target-class gathers: in flight during the whole base loop
  float2 xg[GNUM];
  #pragma unroll
  for (int g=0;g<GNUM;g++) xg[g] = *(const float2*)(cp + (size_t)s_tc[g]*hw);

  int gx0 = off % W, gy0 = off / W;
  int gx1 = gx0+1, gy1 = gy0; if (gx1 >= W){ gx1 = 0; gy1++; }

  const float sc0 = rcpf(1.f + __expf(-CL.x));
  const float sc1 = rcpf(1.f + __expf(-CL.y));
  const float ssc0 = sqf(sc0),   ssc1 = sqf(sc1);     // sqrt(sc)
  const float rssc0 = rcpf(ssc0), rssc1 = rcpf(ssc1); // 1/sqrt(sc)

  // base: 5 batches x 16 float2 loads; products in groups of 8 classes (same order as before)
  float base0=0.f, base1=0.f;
  #pragma unroll 1
  for (int bt=0; bt<5; bt++){
    float2 xv[16];
    #pragma unroll
    for (int j=0;j<16;j++) xv[j] = *(const float2*)(cp + (size_t)(bt*16+j)*hw);
    float pr0=1.f, pr1=1.f;
    #pragma unroll
    for (int j=0;j<8;j++){
      pr0 *= (1.f - ssc0*rsqf(1.f+__expf(-xv[j].x)));
      pr1 *= (1.f - ssc1*rsqf(1.f+__expf(-xv[j].y)));
    }
    base0 -= __logf(pr0);
    base1 -= __logf(pr1);
    pr0=1.f; pr1=1.f;
    #pragma unroll
    for (int j=8;j<16;j++){
      pr0 *= (1.f - ssc0*rsqf(1.f+__expf(-xv[j].x)));
      pr1 *= (1.f - ssc1*rsqf(1.f+__expf(-xv[j].y)));
    }
    base0 -= __logf(pr0);
    base1 -= __logf(pr1);
  }

  // decode boxes
  const float px0=(RX.x+gx0)*s, py0=(RY.x+gy0)*s, pw0=__expf(RW.x)*s, ph0=__expf(RH.x)*s;
  const float px1=(RX.y+gx1)*s, py1=(RY.y+gy1)*s, pw1=__expf(RW.y)*s, ph1=__expf(RH.y)*s;
  const float xc0=(gx0+0.5f)*s, yc0=(gy0+0.5f)*s;
  const float xc1=(gx1+0.5f)*s, yc1=(gy1+0.5f)*s;
  const float q1x0=px0-pw0*0.5f, q2x0=px0+pw0*0.5f, q1y0=py0-ph0*0.5f, q2y0=py0+ph0*0.5f;
  const float q1x1=px1-pw1*0.5f, q2x1=px1+pw1*0.5f, q1y1=py1-ph1*0.5f, q2y1=py1+ph1*0.5f;
  const float areaP0 = pw0*ph0, areaP1 = pw1*ph1;
  const float r = 2.5f*s;

  // single pre-pass: union flag + per-g inter bitmask
  unsigned im0=0u, im1=0u;
  bool un0=false, un1=false;
  #pragma unroll
  for (int g=0;g<GNUM;g++){
    const float bx=s_tb[g][0], by=s_tb[g][1], bw=s_tb[g][2], bh=s_tb[g][3];
    const float b1x=bx-bw*0.5f, b2x=bx+bw*0.5f, b1y=by-bh*0.5f, b2y=by+bh*0.5f;
    const bool inb0 = (xc0>b1x)&&(xc0<b2x)&&(yc0>b1y)&&(yc0<b2y);
    const bool inm0 = (xc0>bx-r)&&(xc0<bx+r)&&(yc0>by-r)&&(yc0<by+r);
    const bool inb1 = (xc1>b1x)&&(xc1<b2x)&&(yc1>b1y)&&(yc1<b2y);
    const bool inm1 = (xc1>bx-r)&&(xc1<bx+r)&&(yc1>by-r)&&(yc1<by+r);
    un0 = un0 || inb0 || inm0;
    un1 = un1 || inb1 || inm1;
    im0 |= (inb0&&inm0) ? (1u<<g) : 0u;
    im1 |= (inb1&&inm1) ? (1u<<g) : 0u;
  }
  const float add0 = un0?0.f:1e9f, add1 = un1?0.f:1e9f;

  // per-g: target-class delta (prefetched) + iou + cost, streamed float2 stores
  const size_t rowb = (size_t)b*GNUM*ATOT + a0;
  #pragma unroll 4
  for (int g=0;g<GNUM;g++){
    const float2 x = xg[g];
    const float e0 = __expf(-x.x), e1 = __expf(-x.y);
    const float rp0 = rssc0*sqf(1.f+e0), rp1 = rssc1*sqf(1.f+e1); // 1/p
    const float cd0 = __logf(fmaxf(rp0-1.f, 1e-30f));
    const float cd1 = __logf(fmaxf(rp1-1.f, 1e-30f));

    const float bx=s_tb[g][0], by=s_tb[g][1], bw=s_tb[g][2], bh=s_tb[g][3];
    const float b1x=bx-bw*0.5f, b2x=bx+bw*0.5f, b1y=by-bh*0.5f, b2y=by+bh*0.5f;
    const float areaB = bw*bh;

    float iw,ih,inte;
    iw = fmaxf(fminf(b2x,q2x0)-fmaxf(b1x,q1x0),0.f);
    ih = fmaxf(fminf(b2y,q2y0)-fmaxf(b1y,q1y0),0.f);
    inte = iw*ih;
    const float iou0 = inte * rcpf(areaB+areaP0-inte+1e-16f);
    iw = fmaxf(fminf(b2x,q2x1)-fmaxf(b1x,q1x1),0.f);
    ih = fmaxf(fminf(b2y,q2y1)-fmaxf(b1y,q1y1),0.f);
    inte = iw*ih;
    const float iou1 = inte * rcpf(areaB+areaP1-inte+1e-16f);

    float2 cst;
    cst.x = base0 + cd0 - 3.f*__logf(iou0+1e-8f) + (((im0>>g)&1u)?0.f:100000.f) + add0;
    cst.y = base1 + cd1 - 3.f*__logf(iou1+1e-8f) + (((im1>>g)&1u)?0.f:100000.f) + add1;
    *(float2*)(cost + rowb + (size_t)g*ATOT) = cst;
  }

  pbox[(size_t)b*ATOT+a0  ] = make_float4(px0,py0,pw0,ph0);
  pbox[(size_t)b*ATOT+a0+1] = make_float4(px1,py1,pw1,ph1);
  *(float2*)(pconf + (size_t)b*ATOT + a0) = make_float2(CL.x, CL.y);
  uchar2 um; um.x = un0?1:0; um.y = un1?1:0;
  *(uchar2*)(unionm + (size_t)b*ATOT + a0) = um;
}

// ---------------- Kernel B1: per-(b,g,wave) top-10 via wave shuffles ----------------
__global__ __launch_bounds__(256) void topk_stage1(
    const float* __restrict__ cost, const float4* __restrict__ pbox,
    const unsigned char* __restrict__ unionm, const float* __restrict__ labels,
    float* __restrict__ cand_c, int* __restrict__ cand_i, float* __restrict__ cand_v)
{
  const int bg   = blockIdx.y;
  const int b    = bg >> 4;
  const int seg  = blockIdx.x;
  const int wave = threadIdx.x >> 6;
  const int lane = threadIdx.x & 63;
  const int wg   = seg*4 + wave;

  const float*  crow = cost + (size_t)bg*ATOT;
  const float4* prow = pbox + (size_t)b*ATOT;
  const unsigned char* urow = unionm + (size_t)b*ATOT;
  const float bx = labels[bg*5+0], by = labels[bg*5+1];
  const float bw = labels[bg*5+2], bh = labels[bg*5+3];
  const float areaB = bw*bh;
  const float b1x=bx-bw*0.5f, b2x=bx+bw*0.5f, b1y=by-bh*0.5f, b2y=by+bh*0.5f;

  const int start = seg*SEG + wave*WSEG;
  const int end   = start + WSEG;

  float cv[10]; int ci[10]; float iv[10];
  #pragma unroll
  for (int k=0;k<10;k++){ cv[k]=FINF; ci[k]=IINF; iv[k]=0.f; }

  for (int a = start + lane; a < end; a += 64){
    float c = crow[a];
    if (c < cv[9] || (c == cv[9] && a < ci[9])){
      float nc=c; int ni=a;
      #pragma unroll
      for (int k=0;k<10;k++){
        bool better = (nc < cv[k]) || (nc==cv[k] && ni<ci[k]);
        float tv=cv[k]; int ti=ci[k];
        cv[k]=better?nc:cv[k]; ci[k]=better?ni:ci[k];
        nc  =better?tv:nc;     ni  =better?ti:ni;
      }
    }
    if (urow[a]){
      float4 pb = prow[a];
      float tlx=fmaxf(b1x, pb.x-pb.z*0.5f), brx=fminf(b2x, pb.x+pb.z*0.5f);
      float tly=fmaxf(b1y, pb.y-pb.w*0.5f), bry=fminf(b2y, pb.y+pb.w*0.5f);
      float iw=fmaxf(brx-tlx,0.f), ih=fmaxf(bry-tly,0.f);
      float inte=iw*ih;
      float io = inte * rcpf(areaB + pb.z*pb.w - inte + 1e-16f);
      if (io > iv[9]){
        float nv=io;
        #pragma unroll
        for (int k=0;k<10;k++){
          bool better = nv > iv[k];
          float tv=iv[k];
          iv[k]=better?nv:iv[k];
          nv  =better?tv:nv;
        }
      }
    }
  }

  float selc = 0.f; int seli = 0;
  #pragma unroll
  for (int r=0;r<10;r++){
    float bv = cv[0]; int bi = ci[0];
    #pragma unroll
    for (int off=32; off>0; off>>=1){
      float ov = __shfl_xor(bv, off);
      int   oi = __shfl_xor(bi, off);
      bool take = (ov < bv) || (ov==bv && oi<bi);
      bv = take?ov:bv; bi = take?oi:bi;
    }
    if (lane == r){ selc = bv; seli = bi; }
    if (cv[0]==bv && ci[0]==bi){
      #pragma unroll
      for (int k=0;k<9;k++){ cv[k]=cv[k+1]; ci[k]=ci[k+1]; }
      cv[9]=FINF; ci[9]=IINF;
    }
  }
  float selv = 0.f;
  #pragma unroll
  for (int r=0;r<10;r++){
    float bv = iv[0]; int bl = lane;
    #pragma unroll
    for (int off=32; off>0; off>>=1){
      float ov = __shfl_xor(bv, off);
      int   ol = __shfl_xor(bl, off);
      bool take = (ov > bv) || (ov==bv && ol<bl);
      bv = take?ov:bv; bl = take?ol:bl;
    }
    if (lane == r) selv = bv;
    if (lane == bl){
      #pragma unroll
      for (int k=0;k<9;k++){ iv[k]=iv[k+1]; }
      iv[9]=0.f;
    }
  }

  if (lane < 10){
    const size_t base = ((size_t)bg*NWAVE + wg)*10 + lane;
    cand_c[base] = selc;
    cand_i[base] = seli;
    cand_v[base] = selv;
  }
}

// ---------------- Kernel B2: merge 32x10 candidates -> top-10 + dyn_k + scatter ----------------
__global__ __launch_bounds__(64) void topk_stage2(
    const float* __restrict__ cand_c, const int* __restrict__ cand_i,
    const float* __restrict__ cand_v, unsigned int* __restrict__ match_mask)
{
  const int bg = blockIdx.x;
  const int b = bg >> 4, g = bg & 15;
  const int lane = threadIdx.x;
  const size_t base = (size_t)bg*NWAVE*10 + lane*5;

  float cv[5]; int ci[5]; float iv[5];
  #pragma unroll
  for (int k=0;k<5;k++){ cv[k]=cand_c[base+k]; ci[k]=cand_i[base+k]; iv[k]=cand_v[base+k]; }

  int seli = 0;
  #pragma unroll
  for (int r=0;r<10;r++){
    float bv = cv[0]; int bi = ci[0];
    #pragma unroll
    for (int off=32; off>0; off>>=1){
      float ov = __shfl_xor(bv, off);
      int   oi = __shfl_xor(bi, off);
      bool take = (ov < bv) || (ov==bv && oi<bi);
      bv = take?ov:bv; bi = take?oi:bi;
    }
    if (lane == r) seli = bi;
    if (cv[0]==bv && ci[0]==bi){
      #pragma unroll
      for (int k=0;k<4;k++){ cv[k]=cv[k+1]; ci[k]=ci[k+1]; }
      cv[4]=FINF; ci[4]=IINF;
    }
  }

  float isum = 0.f;
  #pragma unroll
  for (int r=0;r<10;r++){
    float bv = iv[0]; int bl = lane;
    #pragma unroll
    for (int off=32; off>0; off>>=1){
      float ov = __shfl_xor(bv, off);
      int   ol = __shfl_xor(bl, off);
      bool take = (ov > bv) || (ov==bv && ol<bl);
      bv = take?ov:bv; bl = take?ol:bl;
    }
    isum += bv;
    if (lane == bl){
      #pragma unroll
      for (int k=0;k<4;k++){ iv[k]=iv[k+1]; }
      iv[4]=0.f;
    }
  }

  int dynk = (int)isum;
  if (dynk < 1)  dynk = 1;
  if (dynk > 10) dynk = 10;
  if (lane < dynk)
    atomicOr(&match_mask[(size_t)b*ATOT + seli], 1u<<g);
}

// ---------------- Kernel C: resolve matches + loss accumulation ----------------
__global__ __launch_bounds__(256) void loss_kernel(
    const float* __restrict__ p0, const float* __restrict__ p1, const float* __restrict__ p2,
    const float* __restrict__ labels,
    const float* __restrict__ cost, const float4* __restrict__ pbox,
    const float* __restrict__ pconf, const unsigned int* __restrict__ match_mask,
    float* __restrict__ blocksums)
{
  const int b = blockIdx.y;
  const int a = blockIdx.x*256 + threadIdx.x;
  float lbox=0.f, lconf=0.f, lcls=0.f, fgn=0.f;
  if (a < ATOT){
    unsigned int m = match_mask[(size_t)b*ATOT+a];
    float cl = pconf[(size_t)b*ATOT+a];
    if (m != 0u){
      int gidx;
      if (__popc(m) > 1){
        float best = FINF; int bgi = 0;
        for (int g=0; g<GNUM; g++){
          float c = cost[((size_t)b*GNUM+g)*ATOT + a];
          if (c < best){ best=c; bgi=g; }
        }
        gidx = bgi;
      } else {
        gidx = __ffs(m)-1;
      }
      const float* L = labels + ((size_t)b*GNUM+gidx)*5;
      float bx=L[0], by=L[1], bw=L[2], bh=L[3];
      int tcg=(int)L[4];
      float4 pb = pbox[(size_t)b*ATOT+a];
      float tlx=fmaxf(bx-bw*0.5f, pb.x-pb.z*0.5f);
      float brx=fminf(bx+bw*0.5f, pb.x+pb.z*0.5f);
      float tly=fmaxf(by-bh*0.5f, pb.y-pb.w*0.5f);
      float bry=fminf(by+bh*0.5f, pb.y+pb.w*0.5f);
      float iw=fmaxf(brx-tlx,0.f), ih=fmaxf(bry-tly,0.f);
      float inte=iw*ih;
      float iou = inte * rcpf(bw*bh + pb.z*pb.w - inte + 1e-16f);
      lbox = 1.f - iou*iou;
      lconf = bce(cl, 1.f);
      float miou = iou;
      const float* p; int hw, off, W; float s;
      get_level(p0,p1,p2,a,p,hw,off,W,s);
      const float* bp = p + (size_t)b*(NCLS+5)*hw + off;
      for (int c=0;c<NCLS;c++){
        float x = bp[(size_t)(5+c)*hw];
        float t = (c==tcg)? miou : 0.f;
        lcls += bce(x, t);
      }
      fgn = 1.f;
    } else {
      lconf = bce(cl, 0.f);
    }
  }
  #pragma unroll
  for (int off2=32; off2>0; off2>>=1){
    lbox  += __shfl_down(lbox,  off2);
    lconf += __shfl_down(lconf, off2);
    lcls  += __shfl_down(lcls,  off2);
    fgn   += __shfl_down(fgn,   off2);
  }
  __shared__ float s_red[4][4];
  const int wave = threadIdx.x >> 6;
  if ((threadIdx.x & 63)==0){
    s_red[wave][0]=lbox; s_red[wave][1]=lconf; s_red[wave][2]=lcls; s_red[wave][3]=fgn;
  }
  __syncthreads();
  if (threadIdx.x==0){
    float r0=0,r1=0,r2=0,r3=0;
    #pragma unroll
    for (int w=0;w<4;w++){ r0+=s_red[w][0]; r1+=s_red[w][1]; r2+=s_red[w][2]; r3+=s_red[w][3]; }
    const int bid = blockIdx.y*gridDim.x + blockIdx.x;
    ((float4*)blocksums)[bid] = make_float4(r0,r1,r2,r3);
  }
}

__global__ __launch_bounds__(256) void finalize_kernel(
    const float* __restrict__ blocksums, float* __restrict__ out)
{
  const int tid = threadIdx.x;
  float r0=0,r1=0,r2=0,r3=0;
  for (int i = tid; i < NBLK_TOTAL; i += 256){
    const float4 v = ((const float4*)blocksums)[i];
    r0+=v.x; r1+=v.y; r2+=v.z; r3+=v.w;
  }
  #pragma unroll
  for (int off=32; off>0; off>>=1){
    r0 += __shfl_down(r0, off);
    r1 += __shfl_down(r1, off);
    r2 += __shfl_down(r2, off);
    r3 += __shfl_down(r3, off);
  }
  __shared__ float s_red[4][4];
  const int wave = tid >> 6;
  if ((tid & 63)==0){ s_red[wave][0]=r0; s_red[wave][1]=r1; s_red[wave][2]=r2; s_red[wave][3]=r3; }
  __syncthreads();
  if (tid==0){
    float t0=0,t1=0,t2=0,t3=0;
    #pragma unroll
    for (int w=0;w<4;w++){ t0+=s_red[w][0]; t1+=s_red[w][1]; t2+=s_red[w][2]; t3+=s_red[w][3]; }
    out[0] = (5.f*t0 + t1 + t2) / fmaxf(t3, 1.f);
  }
}

extern "C" void kernel_launch(void* const* d_in, const int* in_sizes, int n_in,
                              void* d_out, int out_size, void* d_ws, size_t ws_size,
                              hipStream_t stream)
{
  const float* p0     = (const float*)d_in[0];
  const float* p1     = (const float*)d_in[1];
  const float* p2     = (const float*)d_in[2];
  const float* labels = (const float*)d_in[3];

  char* ws = (char*)d_ws;
  size_t o = 0;
  float*        cost       = (float*)(ws + o);        o += (size_t)BNUM*GNUM*ATOT*4;
  float4*       pbox       = (float4*)(ws + o);       o += (size_t)BNUM*ATOT*16;
  float*        pconf      = (float*)(ws + o);        o += (size_t)BNUM*ATOT*4;
  unsigned int* match_mask = (unsigned int*)(ws + o); o += (size_t)BNUM*ATOT*4;
  unsigned char* unionm    = (unsigned char*)(ws + o);o += (size_t)BNUM*ATOT;
  o = (o + 255) & ~(size_t)255;
  float*        blocksums  = (float*)(ws + o);        o += (size_t)NBLK_TOTAL*4*4;
  o = (o + 255) & ~(size_t)255;
  float*        cand_c     = (float*)(ws + o);        o += (size_t)256*NWAVE*10*4;
  int*          cand_i     = (int*)(ws + o);          o += (size_t)256*NWAVE*10*4;
  float*        cand_v     = (float*)(ws + o);        o += (size_t)256*NWAVE*10*4;

  hipMemsetAsync(match_mask, 0, (size_t)BNUM*ATOT*4, stream);

  dim3 gridA((QTOT+255)/256, BNUM);                 // 66 x 16, 2 anchors/thread
  decode_cost_kernel<<<gridA, 256, 0, stream>>>(p0,p1,p2,labels,cost,pbox,pconf,unionm);
  dim3 gridT(NSPLIT, BNUM*GNUM);
  topk_stage1<<<gridT, 256, 0, stream>>>(cost, pbox, unionm, labels, cand_c, cand_i, cand_v);
  topk_stage2<<<BNUM*GNUM, 64, 0, stream>>>(cand_c, cand_i, cand_v, match_mask);
  dim3 gridC(NBLK_A, BNUM);
  loss_kernel<<<gridC, 256, 0, stream>>>(p0,p1,p2,labels,cost,pbox,pconf,match_mask,blocksums);
  finalize_kernel<<<1, 256, 0, stream>>>(blocksums, (float*)d_out);
}

// Round 8
// 138.969 us; speedup vs baseline: 1.4007x; 1.0628x over previous
//
#include <hip/hip_runtime.h>
#include <hip/hip_bf16.h>
#include <cstdint>

#define NCLS 80
#define GNUM 16
#define BNUM 16
#define A0   25600
#define A1   6400
#define A2   1600
#define ATOT 33600
#define QTOT 16800                      // ATOT/2 anchor-pairs
#define NBLK_A 132
#define NBLK_TOTAL (NBLK_A*BNUM)        // 2112 blocks in loss grid
#define NSPLIT 8
#define SEG   4200
#define WSEG  1050
#define NWAVE 32
#define FINF  3.4e38f
#define IINF  0x7fffffff

__device__ __forceinline__ float rcpf(float x){ return __builtin_amdgcn_rcpf(x); }
__device__ __forceinline__ float sqf (float x){ return __builtin_amdgcn_sqrtf(x); }
__device__ __forceinline__ float rsqf(float x){ return __builtin_amdgcn_rsqf(x); }

__device__ __forceinline__ float bce(float x, float t){
  float e = __expf(-fabsf(x));
  return fmaxf(x,0.f) - x*t + __logf(1.f + e);
}

__device__ __forceinline__ void get_level(const float* p0, const float* p1, const float* p2,
                                          int a, const float*& p, int& hw, int& off, int& W, float& s)
{
  if (a < A0){ p=p0; hw=A0; off=a; W=160; s=8.f; }
  else if (a < A0+A1){ p=p1; hw=A1; off=a-A0; W=80; s=16.f; }
  else { p=p2; hw=A2; off=a-A0-A1; W=40; s=32.f; }
}

// ---------------- Kernel A: decode + per-(g,a) cost, 2 anchors/thread ----------------
// All register arrays STATICALLY indexed (rule #20): batches of 16 float2 fully
// unrolled; per-g loop fully unrolled so prefetched xg[g] stays in VGPRs.
__global__ __launch_bounds__(256, 4) void decode_cost_kernel(
    const float* __restrict__ p0, const float* __restrict__ p1, const float* __restrict__ p2,
    const float* __restrict__ labels,
    float* __restrict__ cost, float4* __restrict__ pbox, float* __restrict__ pconf,
    unsigned char* __restrict__ unionm)
{
  const int b = blockIdx.y;
  const int q = blockIdx.x*256 + threadIdx.x;
  __shared__ float s_tb[GNUM][4];
  __shared__ int   s_tc[GNUM];
  if (threadIdx.x < GNUM){
    const float* L = labels + ((size_t)b*GNUM + threadIdx.x)*5;
    s_tb[threadIdx.x][0]=L[0]; s_tb[threadIdx.x][1]=L[1];
    s_tb[threadIdx.x][2]=L[2]; s_tb[threadIdx.x][3]=L[3];
    s_tc[threadIdx.x]=(int)L[4];
  }
  __syncthreads();
  if (q >= QTOT) return;
  const int a0 = q*2;

  const float* p; int hw, off, W; float s;
  get_level(p0,p1,p2,a0,p,hw,off,W,s);
  const float* bp = p + (size_t)b*(NCLS+5)*hw + off;

  const float2 RX = *(const float2*)(bp);
  const float2 RY = *(const float2*)(bp + (size_t)hw);
  const float2 RW = *(const float2*)(bp + 2*(size_t)hw);
  const float2 RH = *(const float2*)(bp + 3*(size_t)hw);
  const float2 CL = *(const float2*)(bp + 4*(size_t)hw);
  const float* cp = bp + 5*(size_t)hw;

  // prefetch the 16 target-class gathers (static indexing everywhere below)
  float2 xg[GNUM];
  #pragma unroll
  for (int g=0;g<GNUM;g++) xg[g] = *(const float2*)(cp + (size_t)s_tc[g]*hw);

  int gx0 = off % W, gy0 = off / W;
  int gx1 = gx0+1, gy1 = gy0; if (gx1 >= W){ gx1 = 0; gy1++; }

  const float sc0 = rcpf(1.f + __expf(-CL.x));
  const float sc1 = rcpf(1.f + __expf(-CL.y));
  const float ssc0 = sqf(sc0),   ssc1 = sqf(sc1);     // sqrt(sc)
  const float rssc0 = rcpf(ssc0), rssc1 = rcpf(ssc1); // 1/sqrt(sc)

  // base: 5 batches x 16 float2 loads; products in groups of 8 classes (same order)
  float base0=0.f, base1=0.f;
  #pragma unroll 1
  for (int bt=0; bt<5; bt++){
    float2 xv[16];
    #pragma unroll
    for (int j=0;j<16;j++) xv[j] = *(const float2*)(cp + (size_t)(bt*16+j)*hw);
    float pr0=1.f, pr1=1.f;
    #pragma unroll
    for (int j=0;j<8;j++){
      pr0 *= (1.f - ssc0*rsqf(1.f+__expf(-xv[j].x)));
      pr1 *= (1.f - ssc1*rsqf(1.f+__expf(-xv[j].y)));
    }
    base0 -= __logf(pr0);
    base1 -= __logf(pr1);
    pr0=1.f; pr1=1.f;
    #pragma unroll
    for (int j=8;j<16;j++){
      pr0 *= (1.f - ssc0*rsqf(1.f+__expf(-xv[j].x)));
      pr1 *= (1.f - ssc1*rsqf(1.f+__expf(-xv[j].y)));
    }
    base0 -= __logf(pr0);
    base1 -= __logf(pr1);
  }

  // decode boxes
  const float px0=(RX.x+gx0)*s, py0=(RY.x+gy0)*s, pw0=__expf(RW.x)*s, ph0=__expf(RH.x)*s;
  const float px1=(RX.y+gx1)*s, py1=(RY.y+gy1)*s, pw1=__expf(RW.y)*s, ph1=__expf(RH.y)*s;
  const float xc0=(gx0+0.5f)*s, yc0=(gy0+0.5f)*s;
  const float xc1=(gx1+0.5f)*s, yc1=(gy1+0.5f)*s;
  const float q1x0=px0-pw0*0.5f, q2x0=px0+pw0*0.5f, q1y0=py0-ph0*0.5f, q2y0=py0+ph0*0.5f;
  const float q1x1=px1-pw1*0.5f, q2x1=px1+pw1*0.5f, q1y1=py1-ph1*0.5f, q2y1=py1+ph1*0.5f;
  const float areaP0 = pw0*ph0, areaP1 = pw1*ph1;
  const float r = 2.5f*s;

  const size_t rowb = (size_t)b*GNUM*ATOT + a0;

  // union flags first (needed for the +1e9 term)
  bool un0=false, un1=false;
  #pragma unroll
  for (int g=0;g<GNUM;g++){
    const float bx=s_tb[g][0], by=s_tb[g][1], bw=s_tb[g][2], bh=s_tb[g][3];
    const float b1x=bx-bw*0.5f, b2x=bx+bw*0.5f, b1y=by-bh*0.5f, b2y=by+bh*0.5f;
    un0 = un0 || ((xc0>b1x)&&(xc0<b2x)&&(yc0>b1y)&&(yc0<b2y))
              || ((xc0>bx-r)&&(xc0<bx+r)&&(yc0>by-r)&&(yc0<by+r));
    un1 = un1 || ((xc1>b1x)&&(xc1<b2x)&&(yc1>b1y)&&(yc1<b2y))
              || ((xc1>bx-r)&&(xc1<bx+r)&&(yc1>by-r)&&(yc1<by+r));
  }
  const float add0 = un0?0.f:1e9f, add1 = un1?0.f:1e9f;

  // per-g: FULLY unrolled so xg[g] is a static register reference
  #pragma unroll
  for (int g=0;g<GNUM;g++){
    const float2 x = xg[g];
    const float e0 = __expf(-x.x), e1 = __expf(-x.y);
    const float rp0 = rssc0*sqf(1.f+e0), rp1 = rssc1*sqf(1.f+e1); // 1/p
    const float cd0 = __logf(fmaxf(rp0-1.f, 1e-30f));
    const float cd1 = __logf(fmaxf(rp1-1.f, 1e-30f));

    const float bx=s_tb[g][0], by=s_tb[g][1], bw=s_tb[g][2], bh=s_tb[g][3];
    const float b1x=bx-bw*0.5f, b2x=bx+bw*0.5f, b1y=by-bh*0.5f, b2y=by+bh*0.5f;
    const float areaB = bw*bh;

    const bool inb0 = (xc0>b1x)&&(xc0<b2x)&&(yc0>b1y)&&(yc0<b2y);
    const bool inm0 = (xc0>bx-r)&&(xc0<bx+r)&&(yc0>by-r)&&(yc0<by+r);
    const bool inb1 = (xc1>b1x)&&(xc1<b2x)&&(yc1>b1y)&&(yc1<b2y);
    const bool inm1 = (xc1>bx-r)&&(xc1<bx+r)&&(yc1>by-r)&&(yc1<by+r);

    float iw,ih,inte;
    iw = fmaxf(fminf(b2x,q2x0)-fmaxf(b1x,q1x0),0.f);
    ih = fmaxf(fminf(b2y,q2y0)-fmaxf(b1y,q1y0),0.f);
    inte = iw*ih;
    const float iou0 = inte * rcpf(areaB+areaP0-inte+1e-16f);
    iw = fmaxf(fminf(b2x,q2x1)-fmaxf(b1x,q1x1),0.f);
    ih = fmaxf(fminf(b2y,q2y1)-fmaxf(b1y,q1y1),0.f);
    inte = iw*ih;
    const float iou1 = inte * rcpf(areaB+areaP1-inte+1e-16f);

    float2 cst;
    cst.x = base0 + cd0 - 3.f*__logf(iou0+1e-8f) + ((inb0&&inm0)?0.f:100000.f) + add0;
    cst.y = base1 + cd1 - 3.f*__logf(iou1+1e-8f) + ((inb1&&inm1)?0.f:100000.f) + add1;
    *(float2*)(cost + rowb + (size_t)g*ATOT) = cst;
  }

  pbox[(size_t)b*ATOT+a0  ] = make_float4(px0,py0,pw0,ph0);
  pbox[(size_t)b*ATOT+a0+1] = make_float4(px1,py1,pw1,ph1);
  *(float2*)(pconf + (size_t)b*ATOT + a0) = make_float2(CL.x, CL.y);
  uchar2 um; um.x = un0?1:0; um.y = un1?1:0;
  *(uchar2*)(unionm + (size_t)b*ATOT + a0) = um;
}

// ---------------- Kernel B1: per-(b,g,wave) top-10 via wave shuffles ----------------
__global__ __launch_bounds__(256) void topk_stage1(
    const float* __restrict__ cost, const float4* __restrict__ pbox,
    const unsigned char* __restrict__ unionm, const float* __restrict__ labels,
    float* __restrict__ cand_c, int* __restrict__ cand_i, float* __restrict__ cand_v)
{
  const int bg   = blockIdx.y;
  const int b    = bg >> 4;
  const int seg  = blockIdx.x;
  const int wave = threadIdx.x >> 6;
  const int lane = threadIdx.x & 63;
  const int wg   = seg*4 + wave;

  const float*  crow = cost + (size_t)bg*ATOT;
  const float4* prow = pbox + (size_t)b*ATOT;
  const unsigned char* urow = unionm + (size_t)b*ATOT;
  const float bx = labels[bg*5+0], by = labels[bg*5+1];
  const float bw = labels[bg*5+2], bh = labels[bg*5+3];
  const float areaB = bw*bh;
  const float b1x=bx-bw*0.5f, b2x=bx+bw*0.5f, b1y=by-bh*0.5f, b2y=by+bh*0.5f;

  const int start = seg*SEG + wave*WSEG;
  const int end   = start + WSEG;

  float cv[10]; int ci[10]; float iv[10];
  #pragma unroll
  for (int k=0;k<10;k++){ cv[k]=FINF; ci[k]=IINF; iv[k]=0.f; }

  for (int a = start + lane; a < end; a += 64){
    float c = crow[a];
    if (c < cv[9] || (c == cv[9] && a < ci[9])){
      float nc=c; int ni=a;
      #pragma unroll
      for (int k=0;k<10;k++){
        bool better = (nc < cv[k]) || (nc==cv[k] && ni<ci[k]);
        float tv=cv[k]; int ti=ci[k];
        cv[k]=better?nc:cv[k]; ci[k]=better?ni:ci[k];
        nc  =better?tv:nc;     ni  =better?ti:ni;
      }
    }
    if (urow[a]){
      float4 pb = prow[a];
      float tlx=fmaxf(b1x, pb.x-pb.z*0.5f), brx=fminf(b2x, pb.x+pb.z*0.5f);
      float tly=fmaxf(b1y, pb.y-pb.w*0.5f), bry=fminf(b2y, pb.y+pb.w*0.5f);
      float iw=fmaxf(brx-tlx,0.f), ih=fmaxf(bry-tly,0.f);
      float inte=iw*ih;
      float io = inte * rcpf(areaB + pb.z*pb.w - inte + 1e-16f);
      if (io > iv[9]){
        float nv=io;
        #pragma unroll
        for (int k=0;k<10;k++){
          bool better = nv > iv[k];
          float tv=iv[k];
          iv[k]=better?nv:iv[k];
          nv  =better?tv:nv;
        }
      }
    }
  }

  float selc = 0.f; int seli = 0;
  #pragma unroll
  for (int r=0;r<10;r++){
    float bv = cv[0]; int bi = ci[0];
    #pragma unroll
    for (int off=32; off>0; off>>=1){
      float ov = __shfl_xor(bv, off);
      int   oi = __shfl_xor(bi, off);
      bool take = (ov < bv) || (ov==bv && oi<bi);
      bv = take?ov:bv; bi = take?oi:bi;
    }
    if (lane == r){ selc = bv; seli = bi; }
    if (cv[0]==bv && ci[0]==bi){
      #pragma unroll
      for (int k=0;k<9;k++){ cv[k]=cv[k+1]; ci[k]=ci[k+1]; }
      cv[9]=FINF; ci[9]=IINF;
    }
  }
  float selv = 0.f;
  #pragma unroll
  for (int r=0;r<10;r++){
    float bv = iv[0]; int bl = lane;
    #pragma unroll
    for (int off=32; off>0; off>>=1){
      float ov = __shfl_xor(bv, off);
      int   ol = __shfl_xor(bl, off);
      bool take = (ov > bv) || (ov==bv && ol<bl);
      bv = take?ov:bv; bl = take?ol:bl;
    }
    if (lane == r) selv = bv;
    if (lane == bl){
      #pragma unroll
      for (int k=0;k<9;k++){ iv[k]=iv[k+1]; }
      iv[9]=0.f;
    }
  }

  if (lane < 10){
    const size_t base = ((size_t)bg*NWAVE + wg)*10 + lane;
    cand_c[base] = selc;
    cand_i[base] = seli;
    cand_v[base] = selv;
  }
}

// ---------------- Kernel B2: merge 32x10 candidates -> top-10 + dyn_k + scatter ----------------
__global__ __launch_bounds__(64) void topk_stage2(
    const float* __restrict__ cand_c, const int* __restrict__ cand_i,
    const float* __restrict__ cand_v, unsigned int* __restrict__ match_mask)
{
  const int bg = blockIdx.x;
  const int b = bg >> 4, g = bg & 15;
  const int lane = threadIdx.x;
  const size_t base = (size_t)bg*NWAVE*10 + lane*5;

  float cv[5]; int ci[5]; float iv[5];
  #pragma unroll
  for (int k=0;k<5;k++){ cv[k]=cand_c[base+k]; ci[k]=cand_i[base+k]; iv[k]=cand_v[base+k]; }

  int seli = 0;
  #pragma unroll
  for (int r=0;r<10;r++){
    float bv = cv[0]; int bi = ci[0];
    #pragma unroll
    for (int off=32; off>0; off>>=1){
      float ov = __shfl_xor(bv, off);
      int   oi = __shfl_xor(bi, off);
      bool take = (ov < bv) || (ov==bv && oi<bi);
      bv = take?ov:bv; bi = take?oi:bi;
    }
    if (lane == r) seli = bi;
    if (cv[0]==bv && ci[0]==bi){
      #pragma unroll
      for (int k=0;k<4;k++){ cv[k]=cv[k+1]; ci[k]=ci[k+1]; }
      cv[4]=FINF; ci[4]=IINF;
    }
  }

  float isum = 0.f;
  #pragma unroll
  for (int r=0;r<10;r++){
    float bv = iv[0]; int bl = lane;
    #pragma unroll
    for (int off=32; off>0; off>>=1){
      float ov = __shfl_xor(bv, off);
      int   ol = __shfl_xor(bl, off);
      bool take = (ov > bv) || (ov==bv && ol<bl);
      bv = take?ov:bv; bl = take?ol:bl;
    }
    isum += bv;
    if (lane == bl){
      #pragma unroll
      for (int k=0;k<4;k++){ iv[k]=iv[k+1]; }
      iv[4]=0.f;
    }
  }

  int dynk = (int)isum;
  if (dynk < 1)  dynk = 1;
  if (dynk > 10) dynk = 10;
  if (lane < dynk)
    atomicOr(&match_mask[(size_t)b*ATOT + seli], 1u<<g);
}

// ---------------- Kernel C: resolve matches + loss accumulation ----------------
__global__ __launch_bounds__(256) void loss_kernel(
    const float* __restrict__ p0, const float* __restrict__ p1, const float* __restrict__ p2,
    const float* __restrict__ labels,
    const float* __restrict__ cost, const float4* __restrict__ pbox,
    const float* __restrict__ pconf, const unsigned int* __restrict__ match_mask,
    float* __restrict__ blocksums)
{
  const int b = blockIdx.y;
  const int a = blockIdx.x*256 + threadIdx.x;
  float lbox=0.f, lconf=0.f, lcls=0.f, fgn=0.f;
  if (a < ATOT){
    unsigned int m = match_mask[(size_t)b*ATOT+a];
    float cl = pconf[(size_t)b*ATOT+a];
    if (m != 0u){
      int gidx;
      if (__popc(m) > 1){
        float best = FINF; int bgi = 0;
        for (int g=0; g<GNUM; g++){
          float c = cost[((size_t)b*GNUM+g)*ATOT + a];
          if (c < best){ best=c; bgi=g; }
        }
        gidx = bgi;
      } else {
        gidx = __ffs(m)-1;
      }
      const float* L = labels + ((size_t)b*GNUM+gidx)*5;
      float bx=L[0], by=L[1], bw=L[2], bh=L[3];
      int tcg=(int)L[4];
      float4 pb = pbox[(size_t)b*ATOT+a];
      float tlx=fmaxf(bx-bw*0.5f, pb.x-pb.z*0.5f);
      float brx=fminf(bx+bw*0.5f, pb.x+pb.z*0.5f);
      float tly=fmaxf(by-bh*0.5f, pb.y-pb.w*0.5f);
      float bry=fminf(by+bh*0.5f, pb.y+pb.w*0.5f);
      float iw=fmaxf(brx-tlx,0.f), ih=fmaxf(bry-tly,0.f);
      float inte=iw*ih;
      float iou = inte * rcpf(bw*bh + pb.z*pb.w - inte + 1e-16f);
      lbox = 1.f - iou*iou;
      lconf = bce(cl, 1.f);
      float miou = iou;
      const float* p; int hw, off, W; float s;
      get_level(p0,p1,p2,a,p,hw,off,W,s);
      const float* bp = p + (size_t)b*(NCLS+5)*hw + off;
      for (int c=0;c<NCLS;c++){
        float x = bp[(size_t)(5+c)*hw];
        float t = (c==tcg)? miou : 0.f;
        lcls += bce(x, t);
      }
      fgn = 1.f;
    } else {
      lconf = bce(cl, 0.f);
    }
  }
  #pragma unroll
  for (int off2=32; off2>0; off2>>=1){
    lbox  += __shfl_down(lbox,  off2);
    lconf += __shfl_down(lconf, off2);
    lcls  += __shfl_down(lcls,  off2);
    fgn   += __shfl_down(fgn,   off2);
  }
  __shared__ float s_red[4][4];
  const int wave = threadIdx.x >> 6;
  if ((threadIdx.x & 63)==0){
    s_red[wave][0]=lbox; s_red[wave][1]=lconf; s_red[wave][2]=lcls; s_red[wave][3]=fgn;
  }
  __syncthreads();
  if (threadIdx.x==0){
    float r0=0,r1=0,r2=0,r3=0;
    #pragma unroll
    for (int w=0;w<4;w++){ r0+=s_red[w][0]; r1+=s_red[w][1]; r2+=s_red[w][2]; r3+=s_red[w][3]; }
    const int bid = blockIdx.y*gridDim.x + blockIdx.x;
    ((float4*)blocksums)[bid] = make_float4(r0,r1,r2,r3);
  }
}

__global__ __launch_bounds__(256) void finalize_kernel(
    const float* __restrict__ blocksums, float* __restrict__ out)
{
  const int tid = threadIdx.x;
  float r0=0,r1=0,r2=0,r3=0;
  for (int i = tid; i < NBLK_TOTAL; i += 256){
    const float4 v = ((const float4*)blocksums)[i];
    r0+=v.x; r1+=v.y; r2+=v.z; r3+=v.w;
  }
  #pragma unroll
  for (int off=32; off>0; off>>=1){
    r0 += __shfl_down(r0, off);
    r1 += __shfl_down(r1, off);
    r2 += __shfl_down(r2, off);
    r3 += __shfl_down(r3, off);
  }
  __shared__ float s_red[4][4];
  const int wave = tid >> 6;
  if ((tid & 63)==0){ s_red[wave][0]=r0; s_red[wave][1]=r1; s_red[wave][2]=r2; s_red[wave][3]=r3; }
  __syncthreads();
  if (tid==0){
    float t0=0,t1=0,t2=0,t3=0;
    #pragma unroll
    for (int w=0;w<4;w++){ t0+=s_red[w][0]; t1+=s_red[w][1]; t2+=s_red[w][2]; t3+=s_red[w][3]; }
    out[0] = (5.f*t0 + t1 + t2) / fmaxf(t3, 1.f);
  }
}

extern "C" void kernel_launch(void* const* d_in, const int* in_sizes, int n_in,
                              void* d_out, int out_size, void* d_ws, size_t ws_size,
                              hipStream_t stream)
{
  const float* p0     = (const float*)d_in[0];
  const float* p1     = (const float*)d_in[1];
  const float* p2     = (const float*)d_in[2];
  const float* labels = (const float*)d_in[3];

  char* ws = (char*)d_ws;
  size_t o = 0;
  float*        cost       = (float*)(ws + o);        o += (size_t)BNUM*GNUM*ATOT*4;
  float4*       pbox       = (float4*)(ws + o);       o += (size_t)BNUM*ATOT*16;
  float*        pconf      = (float*)(ws + o);        o += (size_t)BNUM*ATOT*4;
  unsigned int* match_mask = (unsigned int*)(ws + o); o += (size_t)BNUM*ATOT*4;
  unsigned char* unionm    = (unsigned char*)(ws + o);o += (size_t)BNUM*ATOT;
  o = (o + 255) & ~(size_t)255;
  float*        blocksums  = (float*)(ws + o);        o += (size_t)NBLK_TOTAL*4*4;
  o = (o + 255) & ~(size_t)255;
  float*        cand_c     = (float*)(ws + o);        o += (size_t)256*NWAVE*10*4;
  int*          cand_i     = (int*)(ws + o);          o += (size_t)256*NWAVE*10*4;
  float*        cand_v     = (float*)(ws + o);        o += (size_t)256*NWAVE*10*4;

  hipMemsetAsync(match_mask, 0, (size_t)BNUM*ATOT*4, stream);

  dim3 gridA((QTOT+255)/256, BNUM);                 // 66 x 16, 2 anchors/thread
  decode_cost_kernel<<<gridA, 256, 0, stream>>>(p0,p1,p2,labels,cost,pbox,pconf,unionm);
  dim3 gridT(NSPLIT, BNUM*GNUM);
  topk_stage1<<<gridT, 256, 0, stream>>>(cost, pbox, unionm, labels, cand_c, cand_i, cand_v);
  topk_stage2<<<BNUM*GNUM, 64, 0, stream>>>(cand_c, cand_i, cand_v, match_mask);
  dim3 gridC(NBLK_A, BNUM);
  loss_kernel<<<gridC, 256, 0, stream>>>(p0,p1,p2,labels,cost,pbox,pconf,match_mask,blocksums);
  finalize_kernel<<<1, 256, 0, stream>>>(blocksums, (float*)d_out);
}